// Round 1
// baseline (3914.548 us; speedup 1.0000x reference)
//
#include <hip/hip_runtime.h>
#include <hip/hip_bf16.h>
#include <math.h>

#define EPSF 1e-6f
#define NLBL 159
#define HID  1024
#define BATCH 8192

// ---------------- threefry2x32 (exact jax semantics, 20 rounds) ----------------
__device__ inline unsigned rotl32(unsigned x, int d){ return (x<<d)|(x>>(32-d)); }

__device__ inline void threefry2x32(unsigned k0, unsigned k1,
                                    unsigned x0, unsigned x1,
                                    unsigned* o0, unsigned* o1) {
  unsigned ks0=k0, ks1=k1, ks2=k0^k1^0x1BD11BDAu;
  x0 += ks0; x1 += ks1;
#define TF_R(r) { x0 += x1; x1 = rotl32(x1,(r)); x1 ^= x0; }
  TF_R(13) TF_R(15) TF_R(26) TF_R(6)  x0 += ks1; x1 += ks2 + 1u;
  TF_R(17) TF_R(29) TF_R(16) TF_R(24) x0 += ks2; x1 += ks0 + 2u;
  TF_R(13) TF_R(15) TF_R(26) TF_R(6)  x0 += ks0; x1 += ks1 + 3u;
  TF_R(17) TF_R(29) TF_R(16) TF_R(24) x0 += ks1; x1 += ks2 + 4u;
  TF_R(13) TF_R(15) TF_R(26) TF_R(6)  x0 += ks2; x1 += ks0 + 5u;
#undef TF_R
  *o0 = x0; *o1 = x1;
}

// ---------------- generic f32 GEMM: C = act(A(MxK) @ W(NxK)^T + bias) ----------------
template<int RELU>
__global__ __launch_bounds__(256) void gemm_xwt(const float* __restrict__ A,
                                                const float* __restrict__ W,
                                                const float* __restrict__ bias,
                                                float* __restrict__ C,
                                                int M, int N, int K) {
  __shared__ float As[32][68];
  __shared__ float Ws[32][68];
  const int tid = threadIdx.x;
  const int m0 = blockIdx.x * 64;
  const int n0 = blockIdx.y * 64;
  const int tn = tid & 15;
  const int tm = tid >> 4;
  float acc[4][4];
#pragma unroll
  for (int i=0;i<4;++i)
#pragma unroll
    for (int j=0;j<4;++j) acc[i][j]=0.f;

  for (int k0 = 0; k0 < K; k0 += 32) {
    __syncthreads();
#pragma unroll
    for (int s2 = 0; s2 < 8; ++s2) {
      int f = tid + s2*256;
      int kk = f & 31, mm = f >> 5;
      int k = k0 + kk;
      float av = 0.f, wv = 0.f;
      if (k < K) {
        av = A[(size_t)(m0+mm)*K + k];
        int n = n0 + mm;
        if (n < N) wv = W[(size_t)n*K + k];
      }
      As[kk][mm] = av;
      Ws[kk][mm] = wv;
    }
    __syncthreads();
    for (int kk=0; kk<32; ++kk) {
      float4 a4 = *(const float4*)&As[kk][tm*4];
      float4 b4 = *(const float4*)&Ws[kk][tn*4];
      float ai[4] = {a4.x,a4.y,a4.z,a4.w};
      float bj[4] = {b4.x,b4.y,b4.z,b4.w};
#pragma unroll
      for (int i=0;i<4;++i)
#pragma unroll
        for (int j=0;j<4;++j) acc[i][j] = fmaf(ai[i], bj[j], acc[i][j]);
    }
  }
#pragma unroll
  for (int i=0;i<4;++i)
#pragma unroll
    for (int j=0;j<4;++j) {
      int m = m0 + tm*4 + i;
      int n = n0 + tn*4 + j;
      if (n < N) {
        float v = acc[i][j] + bias[n];
        if (RELU) v = fmaxf(v, 0.f);
        C[(size_t)m*N + n] = v;
      }
    }
}

// ---------------- Wg1 (1024x159) -> Wg1T (159x1024) ----------------
__global__ void transpose_wg1(const float* __restrict__ Wg1, float* __restrict__ Wg1T) {
  int idx = blockIdx.x*256 + threadIdx.x;
  if (idx < NLBL*HID) {
    int l = idx >> 10, h = idx & 1023;
    Wg1T[idx] = Wg1[h*NLBL + l];
  }
}

// ---------------- persistent iteration kernel ----------------
// 512 blocks x 256 threads; each block owns 16 rows for all 19 iterations.
// LDS: p1s[159][20] (p1 per row), s_lds[512][20] (s chunk), u_s[159]
// Phase A: thread (rtA=t&1, htA=t>>1) computes z for rows 8*rtA..+7, h = pass*512+4*htA+j (j<4)
// Phase B: thread (rtB=t&1, ltB=t>>1) accumulates back for rows 8*rtB..+7, l = ltB (+128 if ltB<31)
__global__ __launch_bounds__(256, 2) void spen_iter(const float* __restrict__ logits,
                                                    const float* __restrict__ Wg1,
                                                    const float* __restrict__ Wg1T,
                                                    const float* __restrict__ Wg2,
                                                    float* __restrict__ out) {
  __shared__ float p1s[NLBL*20];
  __shared__ float s_lds[512*20];
  __shared__ float u_s[NLBL];

  const int tid = threadIdx.x;
  const int row0 = blockIdx.x * 16;

  // ---- pred0 via threefry (p0 = u, p1 = 1-u), bit-exact vs jax ----
  if (tid < NLBL) {
    unsigned i = 3u*(unsigned)tid + 1u;
    unsigned x0, x1; bool use1;
    if (i < 239u) { x0 = i; x1 = (i == 238u) ? 0u : (239u + i); use1 = false; }
    else          { x0 = i - 239u; x1 = i; use1 = true; }
    unsigned o0, o1;
    threefry2x32(0u, 1u, x0, x1, &o0, &o1);
    unsigned bits = use1 ? o1 : o0;
    u_s[tid] = __uint_as_float((bits >> 9) | 0x3f800000u) - 1.0f;
  }
  __syncthreads();
  for (int idx = tid; idx < NLBL*16; idx += 256) {
    int l = idx >> 4, r = idx & 15;
    p1s[l*20 + r] = 1.0f - u_s[l];
  }
  for (int idx = tid; idx < 16*NLBL; idx += 256) {
    int r = idx / NLBL, l = idx % NLBL;
    float u = u_s[l];
    int o = ((row0 + r)*NLBL + l)*2;
    out[o]   = u;
    out[o+1] = 1.0f - u;
  }

  const int rtA = tid & 1;
  const int htA = tid >> 1;       // 0..127
  const int rtB = rtA;
  const int ltB = htA;            // 0..127
  const bool has2 = (ltB < NLBL - 128);   // l2 = ltB + 128 valid

  float back0[8], back1[8];

  for (int it = 1; it <= 19; ++it) {
    const float lr = 1.0f / sqrtf((float)it);
#pragma unroll
    for (int i=0;i<8;++i) { back0[i]=0.f; back1[i]=0.f; }

    for (int pass = 0; pass < 2; ++pass) {
      __syncthreads();   // p1s updates visible / s_lds free
      // ---------- Phase A: z = p1 @ Wg1T for this h-pass ----------
      const int hbase = pass*512 + 4*htA;
      float zz[8][4];
#pragma unroll
      for (int i=0;i<8;++i)
#pragma unroll
        for (int j=0;j<4;++j) zz[i][j]=0.f;

      const float* wp = Wg1T + hbase;
      const float* pl = &p1s[8*rtA];
      for (int l = 0; l < NLBL; ++l) {
        const float4 w4 = *(const float4*)(wp);
        const float4 a4 = *(const float4*)(pl);
        const float4 b4 = *(const float4*)(pl + 4);
        wp += HID; pl += 20;
        float wj[4] = {w4.x,w4.y,w4.z,w4.w};
        float pi[8] = {a4.x,a4.y,a4.z,a4.w,b4.x,b4.y,b4.z,b4.w};
#pragma unroll
        for (int i=0;i<8;++i)
#pragma unroll
          for (int j=0;j<4;++j) zz[i][j] = fmaf(pi[i], wj[j], zz[i][j]);
      }
      // s = Wg2[h] * sigmoid(z), in place
      const float4 g4 = *(const float4*)(Wg2 + hbase);
      float gj[4] = {g4.x,g4.y,g4.z,g4.w};
#pragma unroll
      for (int i=0;i<8;++i)
#pragma unroll
        for (int j=0;j<4;++j) zz[i][j] = gj[j] / (1.0f + __expf(-zz[i][j]));
      // scatter s -> s_lds[(4*htA+j)][r]
#pragma unroll
      for (int j=0;j<4;++j) {
        float4 v0 = make_float4(zz[0][j],zz[1][j],zz[2][j],zz[3][j]);
        float4 v1 = make_float4(zz[4][j],zz[5][j],zz[6][j],zz[7][j]);
        int base = (4*htA + j)*20 + 8*rtA;
        *(float4*)&s_lds[base]     = v0;
        *(float4*)&s_lds[base + 4] = v1;
      }
      __syncthreads();
      // ---------- Phase B: back += s @ Wg1 for this h-pass ----------
      const float* sp = &s_lds[8*rtB];
      const float* wb = Wg1 + (size_t)(pass*512)*NLBL + ltB;
      for (int hl = 0; hl < 512; ++hl) {
        const float4 sA = *(const float4*)(sp);
        const float4 sB = *(const float4*)(sp + 4);
        sp += 20;
        float si[8] = {sA.x,sA.y,sA.z,sA.w,sB.x,sB.y,sB.z,sB.w};
        const float w0 = wb[0];
#pragma unroll
        for (int i=0;i<8;++i) back0[i] = fmaf(si[i], w0, back0[i]);
        if (has2) {
          const float w1 = wb[128];
#pragma unroll
          for (int i=0;i<8;++i) back1[i] = fmaf(si[i], w1, back1[i]);
        }
        wb += NLBL;
      }
    }

    // ---------- update (cells owned by this thread, no sync needed) ----------
#pragma unroll
    for (int slot = 0; slot < 2; ++slot) {
      if (slot == 1 && !has2) break;
      const int l = ltB + 128*slot;
#pragma unroll
      for (int i=0;i<8;++i) {
        const float bk = (slot == 0) ? back0[i] : back1[i];
        const int r = 8*rtB + i;
        const int row = row0 + r;
        float p1 = p1s[l*20 + r];
        const int o = (row*NLBL + l)*2;
        float p0 = out[o];
        float lgt = logits[row*NLBL + l];
        float g1 = lgt + bk - __logf(p1+EPSF) - p1/(p1+EPSF);
        float g0 =          - __logf(p0+EPSF) - p0/(p0+EPSF);
        float lg1 = lr*g1, lg0 = lr*g0;
        float mx = fmaxf(lg0, lg1);
        float e0 = p0*__expf(lg0-mx);
        float e1 = p1*__expf(lg1-mx);
        float den = e0 + e1 + EPSF;
        float n0 = e0/den, n1 = e1/den;
        out[o]   = n0;
        out[o+1] = n1;
        p1s[l*20 + r] = n1;
      }
    }
    // loop-top __syncthreads() protects p1s for next iteration's phase A
  }
}

extern "C" void kernel_launch(void* const* d_in, const int* in_sizes, int n_in,
                              void* d_out, int out_size, void* d_ws, size_t ws_size,
                              hipStream_t stream) {
  const float* xs  = (const float*)d_in[0];
  const float* Wf1 = (const float*)d_in[1];
  const float* bf1 = (const float*)d_in[2];
  const float* Wf2 = (const float*)d_in[3];
  const float* bf2 = (const float*)d_in[4];
  const float* Wf3 = (const float*)d_in[5];
  const float* bf3 = (const float*)d_in[6];
  const float* Wg1 = (const float*)d_in[7];
  const float* Wg2 = (const float*)d_in[8];
  float* out = (float*)d_out;
  float* ws  = (float*)d_ws;

  float* h1     = ws;                          // 8192*150
  float* h2     = h1 + (size_t)BATCH*150;      // 8192*150
  float* logits = h2 + (size_t)BATCH*150;      // 8192*159
  float* Wg1T   = logits + (size_t)BATCH*NLBL; // 159*1024

  // feature MLP (f32, tiled)
  gemm_xwt<1><<<dim3(BATCH/64, 3), 256, 0, stream>>>(xs, Wf1, bf1, h1, BATCH, 150, 1836);
  gemm_xwt<1><<<dim3(BATCH/64, 3), 256, 0, stream>>>(h1, Wf2, bf2, h2, BATCH, 150, 150);
  gemm_xwt<0><<<dim3(BATCH/64, 3), 256, 0, stream>>>(h2, Wf3, bf3, logits, BATCH, NLBL, 150);

  transpose_wg1<<<(NLBL*HID + 255)/256, 256, 0, stream>>>(Wg1, Wg1T);

  // persistent 19-iteration kernel: 512 blocks x 256 threads, 16 rows/block
  spen_iter<<<BATCH/16, 256, 0, stream>>>(logits, Wg1, Wg1T, Wg2, out);
}

// Round 2
// 1733.657 us; speedup vs baseline: 2.2580x; 2.2580x over previous
//
#include <hip/hip_runtime.h>
#include <hip/hip_bf16.h>
#include <math.h>

#define EPSF 1e-6f
#define NLBL 159
#define NLP  160
#define HID  1024
#define BATCH 8192

typedef __attribute__((ext_vector_type(8))) short short8v;
typedef __attribute__((ext_vector_type(4))) float f32x4;

__device__ inline ushort f2bf(float f) {
  __hip_bfloat16 h = __float2bfloat16(f);
  return *reinterpret_cast<ushort*>(&h);
}

// ---------------- threefry2x32 (exact jax semantics, 20 rounds) ----------------
__device__ inline unsigned rotl32(unsigned x, int d){ return (x<<d)|(x>>(32-d)); }

__device__ inline void threefry2x32(unsigned k0, unsigned k1,
                                    unsigned x0, unsigned x1,
                                    unsigned* o0, unsigned* o1) {
  unsigned ks0=k0, ks1=k1, ks2=k0^k1^0x1BD11BDAu;
  x0 += ks0; x1 += ks1;
#define TF_R(r) { x0 += x1; x1 = rotl32(x1,(r)); x1 ^= x0; }
  TF_R(13) TF_R(15) TF_R(26) TF_R(6)  x0 += ks1; x1 += ks2 + 1u;
  TF_R(17) TF_R(29) TF_R(16) TF_R(24) x0 += ks2; x1 += ks0 + 2u;
  TF_R(13) TF_R(15) TF_R(26) TF_R(6)  x0 += ks0; x1 += ks1 + 3u;
  TF_R(17) TF_R(29) TF_R(16) TF_R(24) x0 += ks1; x1 += ks2 + 4u;
  TF_R(13) TF_R(15) TF_R(26) TF_R(6)  x0 += ks2; x1 += ks0 + 5u;
#undef TF_R
  *o0 = x0; *o1 = x1;
}

// ---------------- generic f32 GEMM: C = act(A(MxK) @ W(NxK)^T + bias) ----------------
template<int RELU>
__global__ __launch_bounds__(256) void gemm_xwt(const float* __restrict__ A,
                                                const float* __restrict__ W,
                                                const float* __restrict__ bias,
                                                float* __restrict__ C,
                                                int M, int N, int K) {
  __shared__ float As[32][68];
  __shared__ float Ws[32][68];
  const int tid = threadIdx.x;
  const int m0 = blockIdx.x * 64;
  const int n0 = blockIdx.y * 64;
  const int tn = tid & 15;
  const int tm = tid >> 4;
  float acc[4][4];
#pragma unroll
  for (int i=0;i<4;++i)
#pragma unroll
    for (int j=0;j<4;++j) acc[i][j]=0.f;

  for (int k0 = 0; k0 < K; k0 += 32) {
    __syncthreads();
#pragma unroll
    for (int s2 = 0; s2 < 8; ++s2) {
      int f = tid + s2*256;
      int kk = f & 31, mm = f >> 5;
      int k = k0 + kk;
      float av = 0.f, wv = 0.f;
      if (k < K) {
        av = A[(size_t)(m0+mm)*K + k];
        int n = n0 + mm;
        if (n < N) wv = W[(size_t)n*K + k];
      }
      As[kk][mm] = av;
      Ws[kk][mm] = wv;
    }
    __syncthreads();
    for (int kk=0; kk<32; ++kk) {
      float4 a4 = *(const float4*)&As[kk][tm*4];
      float4 b4 = *(const float4*)&Ws[kk][tn*4];
      float ai[4] = {a4.x,a4.y,a4.z,a4.w};
      float bj[4] = {b4.x,b4.y,b4.z,b4.w};
#pragma unroll
      for (int i=0;i<4;++i)
#pragma unroll
        for (int j=0;j<4;++j) acc[i][j] = fmaf(ai[i], bj[j], acc[i][j]);
    }
  }
#pragma unroll
  for (int i=0;i<4;++i)
#pragma unroll
    for (int j=0;j<4;++j) {
      int m = m0 + tm*4 + i;
      int n = n0 + tn*4 + j;
      if (n < N) {
        float v = acc[i][j] + bias[n];
        if (RELU) v = fmaxf(v, 0.f);
        C[(size_t)m*N + n] = v;
      }
    }
}

// ---------------- prep: Wg1 (1024x159 f32) -> Wg1b[1024][160] bf16, Wg1Tb[160][1024] bf16 ----------------
__global__ void prep_weights(const float* __restrict__ Wg1,
                             ushort* __restrict__ Wg1b,
                             ushort* __restrict__ Wg1Tb) {
  int idx = blockIdx.x*256 + threadIdx.x;
  if (idx >= HID*NLP) return;
  int h = idx / NLP, l = idx % NLP;
  float v = (l < NLBL) ? Wg1[h*NLBL + l] : 0.f;
  ushort b = f2bf(v);
  Wg1b[h*NLP + l]  = b;
  Wg1Tb[l*HID + h] = b;
}

// ---------------- persistent MFMA iteration kernel ----------------
// 512 blocks x 256 threads (4 waves); each block owns 16 rows for all 19 iters.
// Phase A: z(16x1024) = p1(16x160) @ Wg1b^T   (wave w owns h in [256w, 256w+256))
// Phase B: back(16x160) = s(16x1024) @ Wg1Tb^T (wave w owns l-tiles w, w+4, w+8)
#define PS  164   // f32 row stride p0s/p1s
#define PBS 168   // ushort row stride p1b
#define SBS 1032  // ushort row stride s_b

__global__ __launch_bounds__(256, 2) void spen_iter_mfma(
    const float* __restrict__ logits,
    const ushort* __restrict__ Wg1b,
    const ushort* __restrict__ Wg1Tb,
    const float* __restrict__ Wg2,
    float* __restrict__ out) {
  __shared__ float  p0s[16*PS];
  __shared__ float  p1s[16*PS];
  __shared__ ushort p1b[16*PBS];
  __shared__ ushort s_b[16*SBS];
  __shared__ float  u_s[NLBL];

  const int tid  = threadIdx.x;
  const int wv   = tid >> 6;
  const int lane = tid & 63;
  const int col  = lane & 15;   // n within a 16-wide MFMA tile / A-row m
  const int kg   = lane >> 4;   // k-group 0..3
  const int row0 = blockIdx.x * 16;

  // ---- pred0 via threefry (p0 = u, p1 = 1-u), bit-exact vs jax ----
  if (tid < NLBL) {
    unsigned i = 3u*(unsigned)tid + 1u;
    unsigned x0, x1; bool use1;
    if (i < 239u) { x0 = i; x1 = (i == 238u) ? 0u : (239u + i); use1 = false; }
    else          { x0 = i - 239u; x1 = i; use1 = true; }
    unsigned o0, o1;
    threefry2x32(0u, 1u, x0, x1, &o0, &o1);
    unsigned bits = use1 ? o1 : o0;
    u_s[tid] = __uint_as_float((bits >> 9) | 0x3f800000u) - 1.0f;
  }
  __syncthreads();
  for (int idx = tid; idx < 16*NLP; idx += 256) {
    int m = idx / NLP, l = idx % NLP;
    float u  = (l < NLBL) ? u_s[l] : 0.f;
    float p1 = (l < NLBL) ? (1.0f - u) : 0.f;
    p0s[m*PS + l]  = u;
    p1s[m*PS + l]  = p1;
    p1b[m*PBS + l] = f2bf(p1);
  }

  // ---- per-thread constant preloads ----
  float wg2own[16];
#pragma unroll
  for (int t = 0; t < 16; ++t) wg2own[t] = Wg2[(wv*16 + t)*16 + col];

  const bool has3 = (wv < 2);
  const int l0 = wv*16 + col;
  const int l1 = (wv+4)*16 + col;
  const int l2 = (wv+8)*16 + col;   // valid only if has3
  f32x4 lgv0, lgv1, lgv2;
#pragma unroll
  for (int r = 0; r < 4; ++r) {
    int m = row0 + kg*4 + r;
    lgv0[r] = (l0 < NLBL) ? logits[(size_t)m*NLBL + l0] : 0.f;
    lgv1[r] = (l1 < NLBL) ? logits[(size_t)m*NLBL + l1] : 0.f;
    lgv2[r] = (has3 && l2 < NLBL) ? logits[(size_t)m*NLBL + l2] : 0.f;
  }

  for (int it = 1; it <= 19; ++it) {
    const float lr = 1.0f / sqrtf((float)it);
    __syncthreads();            // p1b ready for all waves
    // ---------------- Phase A: z = p1 @ Wg1^T ----------------
    f32x4 zacc[16];
#pragma unroll
    for (int t = 0; t < 16; ++t) zacc[t] = (f32x4){0.f,0.f,0.f,0.f};
    const int hwbase = wv*256;
#pragma unroll
    for (int kk = 0; kk < 5; ++kk) {
      const int k0 = kk*32 + kg*8;
      short8v af = *(const short8v*)&p1b[col*PBS + k0];
#pragma unroll
      for (int t = 0; t < 16; ++t) {
        const int h = hwbase + t*16 + col;
        short8v bf = *(const short8v*)&Wg1b[(size_t)h*NLP + k0];
        zacc[t] = __builtin_amdgcn_mfma_f32_16x16x32_bf16(af, bf, zacc[t], 0, 0, 0);
      }
    }
    // s = Wg2[h] * sigmoid(z) -> bf16 -> s_b[m][h]
#pragma unroll
    for (int t = 0; t < 16; ++t) {
      const int h = hwbase + t*16 + col;
#pragma unroll
      for (int r = 0; r < 4; ++r) {
        float z = zacc[t][r];
        float s = wg2own[t] / (1.0f + __expf(-z));
        s_b[(kg*4 + r)*SBS + h] = f2bf(s);
      }
    }
    __syncthreads();            // s_b complete
    // ---------------- Phase B: back = s @ Wg1 ----------------
    f32x4 bacc0 = (f32x4){0.f,0.f,0.f,0.f};
    f32x4 bacc1 = (f32x4){0.f,0.f,0.f,0.f};
    f32x4 bacc2 = (f32x4){0.f,0.f,0.f,0.f};
    for (int kk = 0; kk < 32; ++kk) {
      const int k0 = kk*32 + kg*8;
      short8v af = *(const short8v*)&s_b[col*SBS + k0];
      short8v bf0 = *(const short8v*)&Wg1Tb[(size_t)l0*HID + k0];
      bacc0 = __builtin_amdgcn_mfma_f32_16x16x32_bf16(af, bf0, bacc0, 0, 0, 0);
      short8v bf1 = *(const short8v*)&Wg1Tb[(size_t)l1*HID + k0];
      bacc1 = __builtin_amdgcn_mfma_f32_16x16x32_bf16(af, bf1, bacc1, 0, 0, 0);
      if (has3) {
        short8v bf2 = *(const short8v*)&Wg1Tb[(size_t)l2*HID + k0];
        bacc2 = __builtin_amdgcn_mfma_f32_16x16x32_bf16(af, bf2, bacc2, 0, 0, 0);
      }
    }
    // ---------------- update (f32, owned cells) ----------------
#define UPDATE_CELLS(LL, BACC, LGV)                                        \
    if ((LL) < NLBL) {                                                     \
      _Pragma("unroll")                                                    \
      for (int r = 0; r < 4; ++r) {                                        \
        const int m = kg*4 + r;                                            \
        float bk = (BACC)[r];                                              \
        float p1 = p1s[m*PS + (LL)];                                       \
        float p0 = p0s[m*PS + (LL)];                                       \
        float g1 = (LGV)[r] + bk - __logf(p1+EPSF) - p1/(p1+EPSF);         \
        float g0 =               - __logf(p0+EPSF) - p0/(p0+EPSF);         \
        float lg1 = lr*g1, lg0 = lr*g0;                                    \
        float mx = fmaxf(lg0, lg1);                                        \
        float e0 = p0*__expf(lg0-mx);                                      \
        float e1 = p1*__expf(lg1-mx);                                      \
        float den = e0 + e1 + EPSF;                                        \
        float n0 = e0/den, n1 = e1/den;                                    \
        p0s[m*PS + (LL)] = n0;                                             \
        p1s[m*PS + (LL)] = n1;                                             \
        p1b[m*PBS + (LL)] = f2bf(n1);                                      \
      }                                                                    \
    }
    UPDATE_CELLS(l0, bacc0, lgv0)
    UPDATE_CELLS(l1, bacc1, lgv1)
    if (has3) { UPDATE_CELLS(l2, bacc2, lgv2) }
#undef UPDATE_CELLS
  }

  __syncthreads();
  for (int idx = tid; idx < 16*NLBL; idx += 256) {
    int m = idx / NLBL, l = idx % NLBL;
    size_t o = ((size_t)(row0+m)*NLBL + l)*2;
    out[o]   = p0s[m*PS + l];
    out[o+1] = p1s[m*PS + l];
  }
}

extern "C" void kernel_launch(void* const* d_in, const int* in_sizes, int n_in,
                              void* d_out, int out_size, void* d_ws, size_t ws_size,
                              hipStream_t stream) {
  const float* xs  = (const float*)d_in[0];
  const float* Wf1 = (const float*)d_in[1];
  const float* bf1 = (const float*)d_in[2];
  const float* Wf2 = (const float*)d_in[3];
  const float* bf2 = (const float*)d_in[4];
  const float* Wf3 = (const float*)d_in[5];
  const float* bf3 = (const float*)d_in[6];
  const float* Wg1 = (const float*)d_in[7];
  const float* Wg2 = (const float*)d_in[8];
  float* out = (float*)d_out;

  float* h1     = (float*)d_ws;                 // 8192*150
  float* h2     = h1 + (size_t)BATCH*150;       // 8192*150
  float* logits = h2 + (size_t)BATCH*150;       // 8192*159
  ushort* Wg1b  = (ushort*)(logits + (size_t)BATCH*NLBL);  // 1024*160 bf16
  ushort* Wg1Tb = Wg1b + (size_t)HID*NLP;                  // 160*1024 bf16

  // feature MLP (f32, tiled)
  gemm_xwt<1><<<dim3(BATCH/64, 3), 256, 0, stream>>>(xs, Wf1, bf1, h1, BATCH, 150, 1836);
  gemm_xwt<1><<<dim3(BATCH/64, 3), 256, 0, stream>>>(h1, Wf2, bf2, h2, BATCH, 150, 150);
  gemm_xwt<0><<<dim3(BATCH/64, 3), 256, 0, stream>>>(h2, Wf3, bf3, logits, BATCH, NLBL, 150);

  prep_weights<<<(HID*NLP + 255)/256, 256, 0, stream>>>(Wg1, Wg1b, Wg1Tb);

  spen_iter_mfma<<<BATCH/16, 256, 0, stream>>>(logits, Wg1b, Wg1Tb, Wg2, out);
}

// Round 3
// 650.856 us; speedup vs baseline: 6.0145x; 2.6637x over previous
//
#include <hip/hip_runtime.h>
#include <hip/hip_bf16.h>
#include <math.h>

#define EPSF 1e-6f
#define NLBL 159
#define NLP  160
#define HID  1024
#define BATCH 8192
#define MROWS 32
#define PS   164   // f32 row stride p0s/p1s
#define PBS  168   // ushort row stride p1b
#define SBS  1032  // ushort row stride s_b

typedef __attribute__((ext_vector_type(8))) short short8v;
typedef __attribute__((ext_vector_type(4))) float f32x4;

__device__ inline ushort f2bf(float f) {
  __hip_bfloat16 h = __float2bfloat16(f);
  return *reinterpret_cast<ushort*>(&h);
}

// ---------------- threefry2x32 (exact jax semantics, 20 rounds) ----------------
__device__ inline unsigned rotl32(unsigned x, int d){ return (x<<d)|(x>>(32-d)); }

__device__ inline void threefry2x32(unsigned k0, unsigned k1,
                                    unsigned x0, unsigned x1,
                                    unsigned* o0, unsigned* o1) {
  unsigned ks0=k0, ks1=k1, ks2=k0^k1^0x1BD11BDAu;
  x0 += ks0; x1 += ks1;
#define TF_R(r) { x0 += x1; x1 = rotl32(x1,(r)); x1 ^= x0; }
  TF_R(13) TF_R(15) TF_R(26) TF_R(6)  x0 += ks1; x1 += ks2 + 1u;
  TF_R(17) TF_R(29) TF_R(16) TF_R(24) x0 += ks2; x1 += ks0 + 2u;
  TF_R(13) TF_R(15) TF_R(26) TF_R(6)  x0 += ks0; x1 += ks1 + 3u;
  TF_R(17) TF_R(29) TF_R(16) TF_R(24) x0 += ks1; x1 += ks2 + 4u;
  TF_R(13) TF_R(15) TF_R(26) TF_R(6)  x0 += ks2; x1 += ks0 + 5u;
#undef TF_R
  *o0 = x0; *o1 = x1;
}

// ---------------- generic f32 GEMM: C = act(A(MxK) @ W(NxK)^T + bias) ----------------
template<int RELU>
__global__ __launch_bounds__(256) void gemm_xwt(const float* __restrict__ A,
                                                const float* __restrict__ W,
                                                const float* __restrict__ bias,
                                                float* __restrict__ C,
                                                int M, int N, int K) {
  __shared__ float As[32][68];
  __shared__ float Ws[32][68];
  const int tid = threadIdx.x;
  const int m0 = blockIdx.x * 64;
  const int n0 = blockIdx.y * 64;
  const int tn = tid & 15;
  const int tm = tid >> 4;
  float acc[4][4];
#pragma unroll
  for (int i=0;i<4;++i)
#pragma unroll
    for (int j=0;j<4;++j) acc[i][j]=0.f;

  for (int k0 = 0; k0 < K; k0 += 32) {
    __syncthreads();
#pragma unroll
    for (int s2 = 0; s2 < 8; ++s2) {
      int f = tid + s2*256;
      int kk = f & 31, mm = f >> 5;
      int k = k0 + kk;
      float av = 0.f, wv = 0.f;
      if (k < K) {
        av = A[(size_t)(m0+mm)*K + k];
        int n = n0 + mm;
        if (n < N) wv = W[(size_t)n*K + k];
      }
      As[kk][mm] = av;
      Ws[kk][mm] = wv;
    }
    __syncthreads();
    for (int kk=0; kk<32; ++kk) {
      float4 a4 = *(const float4*)&As[kk][tm*4];
      float4 b4 = *(const float4*)&Ws[kk][tn*4];
      float ai[4] = {a4.x,a4.y,a4.z,a4.w};
      float bj[4] = {b4.x,b4.y,b4.z,b4.w};
#pragma unroll
      for (int i=0;i<4;++i)
#pragma unroll
        for (int j=0;j<4;++j) acc[i][j] = fmaf(ai[i], bj[j], acc[i][j]);
    }
  }
#pragma unroll
  for (int i=0;i<4;++i)
#pragma unroll
    for (int j=0;j<4;++j) {
      int m = m0 + tm*4 + i;
      int n = n0 + tn*4 + j;
      if (n < N) {
        float v = acc[i][j] + bias[n];
        if (RELU) v = fmaxf(v, 0.f);
        C[(size_t)m*N + n] = v;
      }
    }
}

// ---------------- prep: Wg1 (1024x159 f32) -> Wg1b[1024][160] bf16, Wg1Tb[160][1024] bf16 ----------------
__global__ void prep_weights(const float* __restrict__ Wg1,
                             ushort* __restrict__ Wg1b,
                             ushort* __restrict__ Wg1Tb) {
  int idx = blockIdx.x*256 + threadIdx.x;
  if (idx >= HID*NLP) return;
  int h = idx / NLP, l = idx % NLP;
  float v = (l < NLBL) ? Wg1[h*NLBL + l] : 0.f;
  ushort b = f2bf(v);
  Wg1b[h*NLP + l]  = b;
  Wg1Tb[l*HID + h] = b;
}

// ---------------- persistent MFMA iteration kernel ----------------
// 256 blocks x 512 threads (8 waves); each block owns 32 rows for all 19 iters.
// Phase A: z(32x1024) = p1(32x160) @ Wg1b^T; waves own h-tile ranges (balanced
//          against Phase B: waves 0,1 get 4 A-tiles, 2,3 get 10, 4-7 get 9).
// Phase B: back(32x160) = s(32x1024) @ Wg1Tb^T; wave w owns l-tile w; waves 0,1
//          also own l-tiles 8,9.
__global__ __launch_bounds__(512, 2) void spen_iter_mfma(
    const float* __restrict__ logits,
    const ushort* __restrict__ Wg1b,
    const ushort* __restrict__ Wg1Tb,
    const float* __restrict__ Wg2,
    float* __restrict__ out) {
  __shared__ float  p0s[MROWS*PS];
  __shared__ float  p1s[MROWS*PS];
  __shared__ ushort p1b[MROWS*PBS];
  __shared__ ushort s_b[MROWS*SBS];
  __shared__ float  u_s[NLBL];

  const int tid  = threadIdx.x;
  const int wv   = tid >> 6;
  const int lane = tid & 63;
  const int col  = lane & 15;
  const int kg   = lane >> 4;
  const int row0 = blockIdx.x * MROWS;

  // ---- pred0 via threefry (p0 = u, p1 = 1-u), bit-exact vs jax ----
  if (tid < NLBL) {
    unsigned i = 3u*(unsigned)tid + 1u;
    unsigned x0, x1; bool use1;
    if (i < 239u) { x0 = i; x1 = (i == 238u) ? 0u : (239u + i); use1 = false; }
    else          { x0 = i - 239u; x1 = i; use1 = true; }
    unsigned o0, o1;
    threefry2x32(0u, 1u, x0, x1, &o0, &o1);
    unsigned bits = use1 ? o1 : o0;
    u_s[tid] = __uint_as_float((bits >> 9) | 0x3f800000u) - 1.0f;
  }
  __syncthreads();
  for (int idx = tid; idx < MROWS*NLP; idx += 512) {
    int m = idx / NLP, l = idx % NLP;
    float u  = (l < NLBL) ? u_s[l] : 0.f;
    float p1 = (l < NLBL) ? (1.0f - u) : 0.f;
    p0s[m*PS + l]  = u;
    p1s[m*PS + l]  = p1;
    p1b[m*PBS + l] = f2bf(p1);
  }

  // ---- Phase A tile range (balanced vs Phase B extra tiles of waves 0,1) ----
  const int acnt   = (wv < 2) ? 4 : ((wv < 4) ? 10 : 9);
  const int astart = (wv < 2) ? 4*wv : ((wv < 4) ? 8 + 10*(wv-2) : 28 + 9*(wv-4));

  // ---- Phase B l-columns + logits preload ----
  const int lA = wv*16 + col;          // always < 128
  const int lB = 128 + wv*16 + col;    // used when wv < 2
  const bool hasB = (wv < 2);
  float lgA[8], lgB[8];
#pragma unroll
  for (int rh = 0; rh < 2; ++rh)
#pragma unroll
    for (int r = 0; r < 4; ++r) {
      int m = row0 + rh*16 + kg*4 + r;
      lgA[rh*4+r] = logits[(size_t)m*NLBL + lA];
      lgB[rh*4+r] = (hasB && lB < NLBL) ? logits[(size_t)m*NLBL + lB] : 0.f;
    }

  for (int it = 1; it <= 19; ++it) {
    const float lr = 1.0f / sqrtf((float)it);
    __syncthreads();            // p1b stable for all waves
    // ---------------- Phase A: z = p1 @ Wg1^T, s = Wg2*sigmoid(z) ----------------
    short8v afr0[5], afr1[5];   // A-frags for row-halves, reused by all tiles
#pragma unroll
    for (int kk = 0; kk < 5; ++kk) {
      afr0[kk] = *(const short8v*)&p1b[col*PBS + kk*32 + kg*8];
      afr1[kk] = *(const short8v*)&p1b[(16+col)*PBS + kk*32 + kg*8];
    }
#pragma unroll 2
    for (int t = astart; t < astart + acnt; ++t) {
      const int h = t*16 + col;
      f32x4 acc0 = (f32x4){0.f,0.f,0.f,0.f};
      f32x4 acc1 = (f32x4){0.f,0.f,0.f,0.f};
      const ushort* wb = &Wg1b[(size_t)h*NLP + kg*8];
#pragma unroll
      for (int kk = 0; kk < 5; ++kk) {
        short8v bf = *(const short8v*)(wb + kk*32);
        acc0 = __builtin_amdgcn_mfma_f32_16x16x32_bf16(afr0[kk], bf, acc0, 0, 0, 0);
        acc1 = __builtin_amdgcn_mfma_f32_16x16x32_bf16(afr1[kk], bf, acc1, 0, 0, 0);
      }
      const float wg2v = Wg2[h];
#pragma unroll
      for (int r = 0; r < 4; ++r) {
        float s0 = wg2v / (1.0f + __expf(-acc0[r]));
        float s1 = wg2v / (1.0f + __expf(-acc1[r]));
        s_b[(kg*4+r)*SBS + h]    = f2bf(s0);
        s_b[(16+kg*4+r)*SBS + h] = f2bf(s1);
      }
    }
    __syncthreads();            // s_b complete
    // ---------------- Phase B: back = s @ Wg1 ----------------
    f32x4 bA0 = (f32x4){0.f,0.f,0.f,0.f};
    f32x4 bA1 = (f32x4){0.f,0.f,0.f,0.f};
    f32x4 bB0 = (f32x4){0.f,0.f,0.f,0.f};
    f32x4 bB1 = (f32x4){0.f,0.f,0.f,0.f};
    if (hasB) {
      const ushort* wtA = &Wg1Tb[(size_t)lA*HID + kg*8];
      const ushort* wtB = &Wg1Tb[(size_t)lB*HID + kg*8];
      const ushort* sp0 = &s_b[col*SBS + kg*8];
      const ushort* sp1 = &s_b[(16+col)*SBS + kg*8];
#pragma unroll 4
      for (int kk = 0; kk < 32; ++kk) {
        short8v bf0 = *(const short8v*)(wtA + kk*32);
        short8v bf1 = *(const short8v*)(wtB + kk*32);
        short8v a0  = *(const short8v*)(sp0 + kk*32);
        short8v a1  = *(const short8v*)(sp1 + kk*32);
        bA0 = __builtin_amdgcn_mfma_f32_16x16x32_bf16(a0, bf0, bA0, 0, 0, 0);
        bA1 = __builtin_amdgcn_mfma_f32_16x16x32_bf16(a1, bf0, bA1, 0, 0, 0);
        bB0 = __builtin_amdgcn_mfma_f32_16x16x32_bf16(a0, bf1, bB0, 0, 0, 0);
        bB1 = __builtin_amdgcn_mfma_f32_16x16x32_bf16(a1, bf1, bB1, 0, 0, 0);
      }
    } else {
      const ushort* wtA = &Wg1Tb[(size_t)lA*HID + kg*8];
      const ushort* sp0 = &s_b[col*SBS + kg*8];
      const ushort* sp1 = &s_b[(16+col)*SBS + kg*8];
#pragma unroll 4
      for (int kk = 0; kk < 32; ++kk) {
        short8v bf0 = *(const short8v*)(wtA + kk*32);
        short8v a0  = *(const short8v*)(sp0 + kk*32);
        short8v a1  = *(const short8v*)(sp1 + kk*32);
        bA0 = __builtin_amdgcn_mfma_f32_16x16x32_bf16(a0, bf0, bA0, 0, 0, 0);
        bA1 = __builtin_amdgcn_mfma_f32_16x16x32_bf16(a1, bf0, bA1, 0, 0, 0);
      }
    }
    // ---------------- update (f32, owned cells) ----------------
#define UPDATE_HALF(LL, MBASE, BACC, LGarr, LGoff)                         \
    if ((LL) < NLBL) {                                                     \
      _Pragma("unroll")                                                    \
      for (int r = 0; r < 4; ++r) {                                        \
        const int m = (MBASE) + kg*4 + r;                                  \
        float bk = (BACC)[r];                                              \
        float p1 = p1s[m*PS + (LL)];                                       \
        float p0 = p0s[m*PS + (LL)];                                       \
        float g1 = (LGarr)[(LGoff)+r] + bk - __logf(p1+EPSF) - p1/(p1+EPSF); \
        float g0 =                        - __logf(p0+EPSF) - p0/(p0+EPSF); \
        float lg1 = lr*g1, lg0 = lr*g0;                                    \
        float mx = fmaxf(lg0, lg1);                                        \
        float e0 = p0*__expf(lg0-mx);                                      \
        float e1 = p1*__expf(lg1-mx);                                      \
        float den = e0 + e1 + EPSF;                                        \
        float n0 = e0/den, n1 = e1/den;                                    \
        p0s[m*PS + (LL)] = n0;                                             \
        p1s[m*PS + (LL)] = n1;                                             \
        p1b[m*PBS + (LL)] = f2bf(n1);                                      \
      }                                                                    \
    }
    UPDATE_HALF(lA, 0,  bA0, lgA, 0)
    UPDATE_HALF(lA, 16, bA1, lgA, 4)
    if (hasB) {
      UPDATE_HALF(lB, 0,  bB0, lgB, 0)
      UPDATE_HALF(lB, 16, bB1, lgB, 4)
    }
#undef UPDATE_HALF
  }

  __syncthreads();
  for (int idx = tid; idx < MROWS*NLBL; idx += 512) {
    int m = idx / NLBL, l = idx % NLBL;
    size_t o = ((size_t)(row0+m)*NLBL + l)*2;
    out[o]   = p0s[m*PS + l];
    out[o+1] = p1s[m*PS + l];
  }
}

extern "C" void kernel_launch(void* const* d_in, const int* in_sizes, int n_in,
                              void* d_out, int out_size, void* d_ws, size_t ws_size,
                              hipStream_t stream) {
  const float* xs  = (const float*)d_in[0];
  const float* Wf1 = (const float*)d_in[1];
  const float* bf1 = (const float*)d_in[2];
  const float* Wf2 = (const float*)d_in[3];
  const float* bf2 = (const float*)d_in[4];
  const float* Wf3 = (const float*)d_in[5];
  const float* bf3 = (const float*)d_in[6];
  const float* Wg1 = (const float*)d_in[7];
  const float* Wg2 = (const float*)d_in[8];
  float* out = (float*)d_out;

  float* h1     = (float*)d_ws;                 // 8192*150
  float* h2     = h1 + (size_t)BATCH*150;       // 8192*150
  float* logits = h2 + (size_t)BATCH*150;       // 8192*159
  ushort* Wg1b  = (ushort*)(logits + (size_t)BATCH*NLBL);  // 1024*160 bf16
  ushort* Wg1Tb = Wg1b + (size_t)HID*NLP;                  // 160*1024 bf16

  // feature MLP (f32, tiled)
  gemm_xwt<1><<<dim3(BATCH/64, 3), 256, 0, stream>>>(xs, Wf1, bf1, h1, BATCH, 150, 1836);
  gemm_xwt<1><<<dim3(BATCH/64, 3), 256, 0, stream>>>(h1, Wf2, bf2, h2, BATCH, 150, 150);
  gemm_xwt<0><<<dim3(BATCH/64, 3), 256, 0, stream>>>(h2, Wf3, bf3, logits, BATCH, NLBL, 150);

  prep_weights<<<(HID*NLP + 255)/256, 256, 0, stream>>>(Wg1, Wg1b, Wg1Tb);

  spen_iter_mfma<<<BATCH/MROWS, 512, 0, stream>>>(logits, Wg1b, Wg1Tb, Wg2, out);
}